// Round 9
// baseline (1328.378 us; speedup 1.0000x reference)
//
#include <hip/hip_runtime.h>

// HyMBA block, MI355X — ROUND 16: resubmit of R15 (container infra failed
// twice; no GPU verdict — same signature as R2 which passed on resubmit).
// scan_kernel block ranges: 0..7 GRU | 8..15 SSM | 16..2063 gate |
// 2064..3087 dx = x.Dw^T (f32 partial straight into `out`).
// One 84KB LDS pool (union of branches) => 1 block/CU: gate/dx never share
// a CU with scan blocks. out_kernel shrinks to K=64+K=128 GEMMs + readback.
// GRU: 12 MFMAs fully independent (4 accs/gate), summed in epilogue.

#define MROWS 16384   // B*N rows
#define SEQ   2048
#define CH    16      // scan staging chunk (timesteps)
#define NCH   (SEQ / CH)
#define SMEM_BYTES 86016   // 84KB: > 80KB so only one block fits per CU

typedef __attribute__((ext_vector_type(8))) short bf16x8;
typedef __attribute__((ext_vector_type(4))) float f32x4;

__device__ __forceinline__ float bf2f(unsigned short u) {
    union { unsigned int i; float f; } c; c.i = ((unsigned int)u) << 16; return c.f;
}
__device__ __forceinline__ unsigned short f2bf(float f) {
    union { float f; unsigned int i; } c; c.f = f;
    unsigned int x = c.i;
    return (unsigned short)((x + 0x7fffu + ((x >> 16) & 1u)) >> 16);
}
// pack two f32 -> two bf16 (RNE) in one VALU instr
__device__ __forceinline__ unsigned int f2bf_pk(float lo, float hi) {
    unsigned int r;
    asm("v_cvt_pk_bf16_f32 %0, %1, %2" : "=v"(r) : "v"(lo), "v"(hi));
    return r;
}
__device__ __forceinline__ float ldin(const void* p, size_t i, int isf32) {
    return isf32 ? ((const float*)p)[i] : bf2f(((const unsigned short*)p)[i]);
}
__device__ __forceinline__ float sigf(float v) { return 1.f / (1.f + __expf(-v)); }
__device__ __forceinline__ float tanhf_fast(float v) { return 2.f * sigf(2.f * v) - 1.f; }

__global__ void sniff_kernel(const unsigned short* __restrict__ x, int* __restrict__ flag) {
    int tid = threadIdx.x;
    int big = 0;
    for (int i = tid; i < 1024; i += 64) {
        unsigned int e = (x[i] >> 7) & 0xFFu;
        big += (e >= 0xC0u) ? 1 : 0;
    }
#pragma unroll
    for (int off = 32; off; off >>= 1) big += __shfl_down(big, off);
    if (tid == 0) { flag[0] = (big >= 4) ? 1 : 0; flag[1] = 0; }
}

__global__ void zero_out_kernel(float* __restrict__ out) {
    size_t i = ((size_t)blockIdx.x * 256 + threadIdx.x) * 16;
#pragma unroll
    for (int u = 0; u < 16; u++) out[i + u] = 0.f;
}

// ---------------- one-time bf16 conversion (x + weights, fused) ----------------
__device__ __forceinline__ void cvt16(const void* src, unsigned short* dst,
                                      size_t i0, int isf32) {
#pragma unroll
    for (int q = 0; q < 2; q++) {
        size_t i = i0 + q * 8;
        if (isf32) {
            const float* s = (const float*)src + i;
            float4 a = *reinterpret_cast<const float4*>(s);
            float4 b = *reinterpret_cast<const float4*>(s + 4);
            union { bf16x8 v; unsigned int u[4]; } u;
            u.u[0] = f2bf_pk(a.x, a.y); u.u[1] = f2bf_pk(a.z, a.w);
            u.u[2] = f2bf_pk(b.x, b.y); u.u[3] = f2bf_pk(b.z, b.w);
            *reinterpret_cast<bf16x8*>(dst + i) = u.v;
        } else {
            *reinterpret_cast<bf16x8*>(dst + i) =
                *reinterpret_cast<const bf16x8*>((const unsigned short*)src + i);
        }
    }
}

// blocks 0..4095: x (16 elems/thr). blocks 4096..4512: weights/biases.
__global__ __launch_bounds__(256) void cvt_all_kernel(
    const void* __restrict__ x,
    const void* __restrict__ Dw,  const void* __restrict__ Wih,
    const void* __restrict__ pw,  const void* __restrict__ Cw,
    const void* __restrict__ Bw,  const void* __restrict__ bih,
    const void* __restrict__ Bb,  const void* __restrict__ Cb,
    const void* __restrict__ Db,  const void* __restrict__ pb,
    unsigned short* __restrict__ xb,
    unsigned short* __restrict__ Dwb,  unsigned short* __restrict__ Wihb,
    unsigned short* __restrict__ pwb,  unsigned short* __restrict__ Cwb,
    unsigned short* __restrict__ Bwb,  unsigned short* __restrict__ bihb,
    unsigned short* __restrict__ Bbb,  unsigned short* __restrict__ Cbb,
    unsigned short* __restrict__ Dbb,  unsigned short* __restrict__ pbb,
    const int* __restrict__ flagp) {
    int isf32 = *flagp;
    int tid = threadIdx.x;
    if (blockIdx.x < 4096) {
        size_t i0 = ((size_t)blockIdx.x * 256 + tid) * 16;
        cvt16(x, xb, i0, isf32);
        return;
    }
    int blk = blockIdx.x - 4096;
    const void* src; unsigned short* dst; size_t base;
    if (blk < 256)      { src = Dw;  dst = Dwb;  base = (size_t)blk * 4096; }
    else if (blk < 352) { src = Wih; dst = Wihb; base = (size_t)(blk - 256) * 4096; }
    else if (blk < 384) { src = pw;  dst = pwb;  base = (size_t)(blk - 352) * 4096; }
    else if (blk < 400) { src = Cw;  dst = Cwb;  base = (size_t)(blk - 384) * 4096; }
    else if (blk < 416) { src = Bw;  dst = Bwb;  base = (size_t)(blk - 400) * 4096; }
    else {
        for (int i = tid; i < 384; i += 256) bihb[i] = f2bf(ldin(bih, i, isf32));
        if (tid < 64) Bbb[tid] = f2bf(ldin(Bb, tid, isf32));
        for (int i = tid; i < 1024; i += 256) {
            Cbb[i] = f2bf(ldin(Cb, i, isf32));
            Dbb[i] = f2bf(ldin(Db, i, isf32));
            pbb[i] = f2bf(ldin(pb, i, isf32));
        }
        return;
    }
    cvt16(src, dst, base + (size_t)tid * 16, isf32);
}

// ---------------- MFMA GEMM helpers ----------------
// 256-thread staging of a 128x32 tile
__device__ __forceinline__ void stage_tile(const void* __restrict__ g,
                                           int ld, int row0, int rowmax, int kb,
                                           short (*lds)[40], int tid, int isf32) {
#pragma unroll
    for (int q = 0; q < 2; q++) {
        int oct = q * 256 + tid;
        int row = oct >> 2, c8 = (oct & 3) << 3;
        int gr = row0 + row; if (gr > rowmax) gr = rowmax;
        size_t base = (size_t)gr * ld + kb + c8;
        bf16x8 v;
        if (isf32) {
            const float* gp = (const float*)g + base;
            float4 f0 = *reinterpret_cast<const float4*>(gp);
            float4 f1 = *reinterpret_cast<const float4*>(gp + 4);
            union { bf16x8 v8; unsigned int u[4]; } u;
            u.u[0] = f2bf_pk(f0.x, f0.y);
            u.u[1] = f2bf_pk(f0.z, f0.w);
            u.u[2] = f2bf_pk(f1.x, f1.y);
            u.u[3] = f2bf_pk(f1.z, f1.w);
            v = u.v8;
        } else {
            v = *reinterpret_cast<const bf16x8*>((const unsigned short*)g + base);
        }
        *reinterpret_cast<bf16x8*>(&lds[row][c8]) = v;
    }
}

// 512-thread staging of a 128x32 tile (no bounds: dims are exact multiples)
__device__ __forceinline__ void stage512(const void* __restrict__ g,
                                         int ld, int row0, int kb,
                                         short (*lds)[40], int tid, int isf32) {
    int row = tid >> 2, c8 = (tid & 3) << 3;
    size_t base = (size_t)(row0 + row) * ld + kb + c8;
    bf16x8 v;
    if (isf32) {
        const float* gp = (const float*)g + base;
        float4 f0 = *reinterpret_cast<const float4*>(gp);
        float4 f1 = *reinterpret_cast<const float4*>(gp + 4);
        union { bf16x8 v8; unsigned int u[4]; } u;
        u.u[0] = f2bf_pk(f0.x, f0.y);
        u.u[1] = f2bf_pk(f0.z, f0.w);
        u.u[2] = f2bf_pk(f1.x, f1.y);
        u.u[3] = f2bf_pk(f1.z, f1.w);
        v = u.v8;
    } else {
        v = *reinterpret_cast<const bf16x8*>((const unsigned short*)g + base);
    }
    *reinterpret_cast<bf16x8*>(&lds[row][c8]) = v;
}

// A-frag: m=lane&15, k=(lane>>4)*8+j ; B-frag: n=lane&15 (W stored [n][k]).
// C/D: col=lane&15, row=(lane>>4)*4+reg   [m89-verified]
__device__ __forceinline__ void mfma_tiles(const short (*As)[40], const short (*Bs)[40],
                                           int wm, int wn, int lane, f32x4 (*acc)[4]) {
    bf16x8 af[4], bfr[4];
    int m = lane & 15, ko = (lane >> 4) << 3;
#pragma unroll
    for (int i = 0; i < 4; i++)
        af[i] = *reinterpret_cast<const bf16x8*>(&As[wm + i * 16 + m][ko]);
#pragma unroll
    for (int j = 0; j < 4; j++)
        bfr[j] = *reinterpret_cast<const bf16x8*>(&Bs[wn + j * 16 + m][ko]);
#pragma unroll
    for (int i = 0; i < 4; i++)
#pragma unroll
        for (int j = 0; j < 4; j++)
            acc[i][j] = __builtin_amdgcn_mfma_f32_16x16x32_bf16(af[i], bfr[j], acc[i][j], 0, 0, 0);
}

// fused ih+bx GEMM: y<3 -> C1=A.Wih^T (N=384), y==3 -> C2=A.Bw^T (N=64). K=1024.
__global__ __launch_bounds__(256) void gemm_fused_kernel(
    const void* __restrict__ A,
    const void* __restrict__ Wih, const void* __restrict__ bih, unsigned short* __restrict__ C1,
    const void* __restrict__ Bw,  const void* __restrict__ Bb,  unsigned short* __restrict__ C2,
    const int* __restrict__ flagp) {
    __shared__ __align__(16) short As[128][40];
    __shared__ __align__(16) short Bs[128][40];
    int isf32 = *flagp;
    int tid = threadIdx.x, lane = tid & 63, wave = tid >> 6;
    int wm = (wave >> 1) << 6, wn = (wave & 1) << 6;
    int tileM = blockIdx.x << 7;
    const void* W; const void* bias; unsigned short* C; int N, tileN;
    if (blockIdx.y < 3) { W = Wih; bias = bih; C = C1; N = 384; tileN = blockIdx.y << 7; }
    else                { W = Bw;  bias = Bb;  C = C2; N = 64;  tileN = 0; }
    f32x4 acc[4][4];
    f32x4 z = {0.f, 0.f, 0.f, 0.f};
#pragma unroll
    for (int i = 0; i < 4; i++)
#pragma unroll
        for (int j = 0; j < 4; j++) acc[i][j] = z;

    for (int kb = 0; kb < 1024; kb += 32) {
        __syncthreads();
        stage_tile(A, 1024, tileM, MROWS - 1, kb, As, tid, isf32);
        stage_tile(W, 1024, tileN, N - 1, kb, Bs, tid, isf32);
        __syncthreads();
        mfma_tiles(As, Bs, wm, wn, lane, acc);
    }
#pragma unroll
    for (int i = 0; i < 4; i++) {
#pragma unroll
        for (int j = 0; j < 4; j++) {
            int col = tileN + wn + j * 16 + (lane & 15);
            if (col < N) {
                float bv = ldin(bias, col, isf32);
                int row0 = tileM + wm + i * 16 + ((lane >> 4) << 2);
                unsigned int pk0 = f2bf_pk(acc[i][j][0] + bv, acc[i][j][1] + bv);
                unsigned int pk1 = f2bf_pk(acc[i][j][2] + bv, acc[i][j][3] + bv);
                C[(size_t)(row0 + 0) * N + col] = (unsigned short)(pk0 & 0xFFFFu);
                C[(size_t)(row0 + 1) * N + col] = (unsigned short)(pk0 >> 16);
                C[(size_t)(row0 + 2) * N + col] = (unsigned short)(pk1 & 0xFFFFu);
                C[(size_t)(row0 + 3) * N + col] = (unsigned short)(pk1 >> 16);
            }
        }
    }
}

// ---------------- scan + hidden gate + hidden dx GEMM ----------------
// blocks 0..7 GRU | 8..15 SSM | 16..2063 gate | 2064..3087 dx (x.Dw^T -> out f32)
__global__ __launch_bounds__(512) void scan_kernel(
    const void* __restrict__ Amat,            // [64][64]
    const void* __restrict__ Whh,             // [384][128]
    const void* __restrict__ bhh,             // [384]
    const unsigned short* __restrict__ bxw,   // [MROWS][64]  bf16 (Bb included)
    const unsigned short* __restrict__ ihw,   // [MROWS][384] bf16 (b_ih included)
    unsigned short* __restrict__ hsw,         // [MROWS][64]
    unsigned short* __restrict__ hrw,         // [MROWS][128]
    const void* __restrict__ x,  const void* __restrict__ gw,
    const void* __restrict__ gb, float* __restrict__ gx,
    const void* __restrict__ xd, const void* __restrict__ Dwd,
    float* __restrict__ outp,
    const int* __restrict__ flagp, const int* __restrict__ dxflagp) {
    __shared__ __align__(16) char smem[SMEM_BYTES];
    int isf32 = *flagp;
    f32x4 zf = {0.f, 0.f, 0.f, 0.f};

    if (blockIdx.x >= 2064) {
        // ---------------- dx = x . Dw^T, f32 partial into out ----------------
        int bid = (int)blockIdx.x - 2064;            // 0..1023
        int tileM = (bid >> 3) << 7, tileN = (bid & 7) << 7;
        int dxf = *dxflagp;
        short (*As)[40] = (short(*)[40])smem;
        short (*Bs)[40] = (short(*)[40])(smem + 10240);
        int tid = threadIdx.x, lane = tid & 63, wave = tid >> 6;
        int wm = (wave >> 2) << 6;                   // 0,64
        int wn = (wave & 3) << 5;                    // 0,32,64,96
        f32x4 acc[4][2];
#pragma unroll
        for (int i = 0; i < 4; i++)
#pragma unroll
            for (int j = 0; j < 2; j++) acc[i][j] = zf;
        for (int kb = 0; kb < 1024; kb += 32) {
            __syncthreads();
            stage512(xd,  1024, tileM, kb, As, tid, dxf);
            stage512(Dwd, 1024, tileN, kb, Bs, tid, dxf);
            __syncthreads();
            bf16x8 af[4], bfr[2];
            int m = lane & 15, ko = (lane >> 4) << 3;
#pragma unroll
            for (int i = 0; i < 4; i++)
                af[i] = *reinterpret_cast<const bf16x8*>(&As[wm + i * 16 + m][ko]);
#pragma unroll
            for (int j = 0; j < 2; j++)
                bfr[j] = *reinterpret_cast<const bf16x8*>(&Bs[wn + j * 16 + m][ko]);
#pragma unroll
            for (int i = 0; i < 4; i++)
#pragma unroll
                for (int j = 0; j < 2; j++)
                    acc[i][j] = __builtin_amdgcn_mfma_f32_16x16x32_bf16(af[i], bfr[j], acc[i][j], 0, 0, 0);
        }
#pragma unroll
        for (int i = 0; i < 4; i++) {
            int row0 = tileM + wm + i * 16 + ((lane >> 4) << 2);
#pragma unroll
            for (int j = 0; j < 2; j++) {
                int col = tileN + wn + j * 16 + (lane & 15);
#pragma unroll
                for (int r = 0; r < 4; r++)
                    outp[(size_t)(row0 + r) * 1024 + col] = acc[i][j][r];
            }
        }
        return;
    }

    if (blockIdx.x >= 16) {
        // ---------------- gate (hidden under scan) ----------------
        int row = (int)(blockIdx.x - 16) * 8 + (threadIdx.x >> 6);
        int lane = threadIdx.x & 63;
        size_t xoff = (size_t)row * 1024 + lane * 16;
        float a0 = 0.f, a1 = 0.f;
#pragma unroll
        for (int q = 0; q < 2; q++) {
#pragma unroll
            for (int e = 0; e < 8; e++) {
                size_t k = q * 8 + e;
                float xf = ldin(x, xoff + k, isf32);
                a0 += xf * ldin(gw, (size_t)lane * 16 + k, isf32);
                a1 += xf * ldin(gw, 1024 + (size_t)lane * 16 + k, isf32);
            }
        }
#pragma unroll
        for (int off = 32; off > 0; off >>= 1) {
            a0 += __shfl_down(a0, off);
            a1 += __shfl_down(a1, off);
        }
        if (lane == 0) {
            gx[row * 2]     = sigf(a0 + ldin(gb, 0, isf32));
            gx[row * 2 + 1] = sigf(a1 + ldin(gb, 1, isf32));
        }
        return;
    }

    int b = blockIdx.x & 7;
    size_t rowbase = (size_t)b * SEQ;

    if (blockIdx.x < 8) {
        // ---------------- GRU (8 waves) ----------------
        unsigned short (*H)[128] = (unsigned short(*)[128])smem;             // 512B
        unsigned short (*IH)[CH][384] = (unsigned short(*)[CH][384])(smem + 512); // 24576B
        int tid = threadIdx.x, lane = tid & 63, w = tid >> 6;    // w in 0..7
        int col = lane & 15, quad = lane >> 4;
        int o = w * 16 + col;                                    // this wave's col
        if (tid < 256) ((unsigned short*)smem)[tid] = 0;
        // static B-fragments: g=0(r),1(z),2(n): Whh row g*128+o, k = c*32+quad*8+e
        bf16x8 Bf[3][4];
#pragma unroll
        for (int g = 0; g < 3; g++) {
            int n = g * 128 + o;
#pragma unroll
            for (int c = 0; c < 4; c++) {
                int k0 = c * 32 + quad * 8;
                bf16x8 v;
#pragma unroll
                for (int e = 0; e < 8; e++)
                    v[e] = (short)f2bf(ldin(Whh, (size_t)n * 128 + k0 + e, isf32));
                Bf[g][c] = v;
            }
        }
        float bias_r = ldin(bhh, o, isf32);
        float bias_z = ldin(bhh, 128 + o, isf32);
        float bias_n = ldin(bhh, 256 + o, isf32);
        float hprev = 0.f;
        bool gl = (quad == 0);
        // chunk prologue: chunk0 -> IH[0]; issue chunk1 loads (768 bf16x8/chunk)
        const unsigned short* ihbase = ihw + rowbase * 384;
        bf16x8 stg0, stg1;
        stg0 = *reinterpret_cast<const bf16x8*>(ihbase + (size_t)tid * 8);
        if (tid < 256) stg1 = *reinterpret_cast<const bf16x8*>(ihbase + (size_t)(512 + tid) * 8);
        *reinterpret_cast<bf16x8*>(&IH[0][0][0] + (size_t)tid * 8) = stg0;
        if (tid < 256) *reinterpret_cast<bf16x8*>(&IH[0][0][0] + (size_t)(512 + tid) * 8) = stg1;
        stg0 = *reinterpret_cast<const bf16x8*>(ihbase + (size_t)CH * 384 + (size_t)tid * 8);
        if (tid < 256) stg1 = *reinterpret_cast<const bf16x8*>(ihbase + (size_t)CH * 384 + (size_t)(512 + tid) * 8);
        __syncthreads();

        int p = 0;
        auto gru_step = [&](int t, int cur, int tt) {
            // broadcast A-frags: uniform per quad (4 addrs/wave)
            bf16x8 Af[4];
#pragma unroll
            for (int cc = 0; cc < 4; cc++)
                Af[cc] = *reinterpret_cast<const bf16x8*>(&H[p][cc * 32 + quad * 8]);
            float ir  = bf2f(IH[cur][tt][o]);
            float iz  = bf2f(IH[cur][tt][128 + o]);
            float inn = bf2f(IH[cur][tt][256 + o]);
            // 3 gates x 4 fully independent MFMAs (sum in epilogue)
            f32x4 a[3][4];
#pragma unroll
            for (int g = 0; g < 3; g++)
#pragma unroll
                for (int c = 0; c < 4; c++)
                    a[g][c] = __builtin_amdgcn_mfma_f32_16x16x32_bf16(Af[c], Bf[g][c], zf, 0, 0, 0);
            float sr = (a[0][0][0] + a[0][1][0]) + (a[0][2][0] + a[0][3][0]);
            float sz = (a[1][0][0] + a[1][1][0]) + (a[1][2][0] + a[1][3][0]);
            float sn = (a[2][0][0] + a[2][1][0]) + (a[2][2][0] + a[2][3][0]);
            float r  = sigf(ir + sr + bias_r);
            float zg = sigf(iz + sz + bias_z);
            float n  = tanhf_fast(inn + r * (sn + bias_n));
            float hnew = (1.f - zg) * n + zg * hprev;
            hprev = hnew;
            if (gl) {
                unsigned short hb = f2bf(hnew);
                H[p ^ 1][o] = hb;
                hrw[(rowbase + t) * 128 + o] = hb;
            }
            asm volatile("s_waitcnt lgkmcnt(0)" ::: "memory");
            __builtin_amdgcn_s_barrier();
            asm volatile("" ::: "memory");
            p ^= 1;
        };

        for (int c = 0; c < NCH; c++) {
            int cur = c & 1;
            for (int tt = 0; tt < 8; tt++) gru_step(c * CH + tt, cur, tt);
            // mid-chunk staging: write chunk c+1 (loaded ~CH steps ago),
            // issue chunk c+2 loads — drains at next step's barrier
            if (c + 1 < NCH) {
                unsigned short* dst = &IH[(c + 1) & 1][0][0];
                *reinterpret_cast<bf16x8*>(dst + (size_t)tid * 8) = stg0;
                if (tid < 256) *reinterpret_cast<bf16x8*>(dst + (size_t)(512 + tid) * 8) = stg1;
                if (c + 2 < NCH) {
                    const unsigned short* src = ihbase + (size_t)(c + 2) * CH * 384;
                    stg0 = *reinterpret_cast<const bf16x8*>(src + (size_t)tid * 8);
                    if (tid < 256) stg1 = *reinterpret_cast<const bf16x8*>(src + (size_t)(512 + tid) * 8);
                }
            }
            for (int tt = 8; tt < CH; tt++) gru_step(c * CH + tt, cur, tt);
        }
    } else {
        // ---------------- SSM (wave 0 only) ----------------
        if (threadIdx.x >= 64) return;
        int lane = threadIdx.x, col = lane & 15, quad = lane >> 4;
        unsigned short (*Hs)[64] = (unsigned short(*)[64])smem;              // 256B
        unsigned short (*BX)[CH][64] = (unsigned short(*)[CH][64])(smem + 256); // 4096B
        ((unsigned short*)smem)[lane] = 0;
        ((unsigned short*)smem)[64 + lane] = 0;
        bf16x8 Bf[4][2];
#pragma unroll
        for (int l = 0; l < 4; l++) {
            int n = l * 16 + col;
#pragma unroll
            for (int c = 0; c < 2; c++) {
                int k0 = c * 32 + quad * 8;
                bf16x8 v;
#pragma unroll
                for (int e = 0; e < 8; e++)
                    v[e] = (short)f2bf(ldin(Amat, (size_t)n * 64 + k0 + e, isf32));
                Bf[l][c] = v;
            }
        }
        bool gl = (quad == 0);
        const unsigned short* bxbase = bxw + rowbase * 64;
        bf16x8 stg[2];
#pragma unroll
        for (int q = 0; q < 2; q++)
            stg[q] = *reinterpret_cast<const bf16x8*>(bxbase + (size_t)(q * 64 + lane) * 8);
#pragma unroll
        for (int q = 0; q < 2; q++)
            *reinterpret_cast<bf16x8*>(&BX[0][0][0] + (size_t)(q * 64 + lane) * 8) = stg[q];
#pragma unroll
        for (int q = 0; q < 2; q++)
            stg[q] = *reinterpret_cast<const bf16x8*>(bxbase + (size_t)CH * 64 + (size_t)(q * 64 + lane) * 8);
        asm volatile("s_waitcnt lgkmcnt(0)" ::: "memory");

        int p = 0;
        auto ssm_step = [&](int t, int cur, int tt) {
            bf16x8 Af[2];
#pragma unroll
            for (int cc = 0; cc < 2; cc++)
                Af[cc] = *reinterpret_cast<const bf16x8*>(&Hs[p][cc * 32 + quad * 8]);
            float bx[4];
#pragma unroll
            for (int l = 0; l < 4; l++) bx[l] = bf2f(BX[cur][tt][l * 16 + col]);
            f32x4 acc[4];
#pragma unroll
            for (int l = 0; l < 4; l++) {
                acc[l] = __builtin_amdgcn_mfma_f32_16x16x32_bf16(Af[0], Bf[l][0], zf, 0, 0, 0);
                acc[l] = __builtin_amdgcn_mfma_f32_16x16x32_bf16(Af[1], Bf[l][1], acc[l], 0, 0, 0);
            }
#pragma unroll
            for (int l = 0; l < 4; l++) {
                int o = l * 16 + col;
                float v = acc[l][0] + bx[l];
                float hv = v * sigf(v);
                unsigned short hb = f2bf(hv);
                if (gl) {
                    Hs[p ^ 1][o] = hb;
                    hsw[(rowbase + t) * 64 + o] = hb;
                }
            }
            asm volatile("s_waitcnt lgkmcnt(0)" ::: "memory");
            p ^= 1;
        };

        for (int c = 0; c < NCH; c++) {
            int cur = c & 1;
            for (int tt = 0; tt < 8; tt++) ssm_step(c * CH + tt, cur, tt);
            if (c + 1 < NCH) {
                unsigned short* dst = &BX[(c + 1) & 1][0][0];
#pragma unroll
                for (int q = 0; q < 2; q++)
                    *reinterpret_cast<bf16x8*>(dst + (size_t)(q * 64 + lane) * 8) = stg[q];
                if (c + 2 < NCH) {
#pragma unroll
                    for (int q = 0; q < 2; q++)
                        stg[q] = *reinterpret_cast<const bf16x8*>(
                            bxbase + (size_t)(c + 2) * CH * 64 + (size_t)(q * 64 + lane) * 8);
                }
            }
            for (int tt = 8; tt < CH; tt++) ssm_step(c * CH + tt, cur, tt);
        }
    }
}

// out[row,col] = g0*(dx_partial + hs.Cw^T + Cb + Db) + g1*(hr.pw^T + pb)
// dx_partial = x.Dw^T already in `out` (written by scan_kernel's dx blocks).
__global__ __launch_bounds__(256) void out_kernel(
    const void* __restrict__ Db,
    const unsigned short* __restrict__ hs, const void* __restrict__ Cw, const void* __restrict__ Cb,
    const unsigned short* __restrict__ hr, const void* __restrict__ pw, const void* __restrict__ pb,
    const float* __restrict__ gx, float* __restrict__ out,
    const int* __restrict__ flagp) {
    __shared__ __align__(16) short As[128][40];
    __shared__ __align__(16) short Bs[128][40];
    int isf32 = *flagp;
    int tid = threadIdx.x, lane = tid & 63, wave = tid >> 6;
    int wm = (wave >> 1) << 6, wn = (wave & 1) << 6;
    int tileM = blockIdx.x << 7, tileN = blockIdx.y << 7;
    f32x4 z = {0.f, 0.f, 0.f, 0.f};
    f32x4 acc1[4][4], acc2[4][4];
#pragma unroll
    for (int i = 0; i < 4; i++)
#pragma unroll
        for (int j = 0; j < 4; j++) { acc1[i][j] = z; acc2[i][j] = z; }

    for (int kb = 0; kb < 64; kb += 32) {          // hs . Cw^T
        __syncthreads();
        stage_tile(hs, 64, tileM, MROWS - 1, kb, As, tid, 0);
        stage_tile(Cw, 64, tileN, 1023, kb, Bs, tid, isf32);
        __syncthreads();
        mfma_tiles(As, Bs, wm, wn, lane, acc1);
    }
    for (int kb = 0; kb < 128; kb += 32) {         // hr . pw^T
        __syncthreads();
        stage_tile(hr, 128, tileM, MROWS - 1, kb, As, tid, 0);
        stage_tile(pw, 128, tileN, 1023, kb, Bs, tid, isf32);
        __syncthreads();
        mfma_tiles(As, Bs, wm, wn, lane, acc2);
    }
#pragma unroll
    for (int i = 0; i < 4; i++) {
        int r0 = tileM + wm + i * 16 + ((lane >> 4) << 2);
#pragma unroll
        for (int j = 0; j < 4; j++) {
            int col = tileN + wn + j * 16 + (lane & 15);
            float cb  = ldin(Cb, col, isf32) + ldin(Db, col, isf32);
            float pbv = ldin(pb, col, isf32);
#pragma unroll
            for (int r = 0; r < 4; r++) {
                int row = r0 + r;
                float g0 = gx[row * 2], g1 = gx[row * 2 + 1];
                float dxv = out[(size_t)row * 1024 + col];
                out[(size_t)row * 1024 + col] =
                    g0 * (acc1[i][j][r] + dxv + cb) + g1 * (acc2[i][j][r] + pbv);
            }
        }
    }
}

extern "C" void kernel_launch(void* const* d_in, const int* in_sizes, int n_in,
                              void* d_out, int out_size, void* d_ws, size_t ws_size,
                              hipStream_t stream) {
    static const int expect_sizes[16] = {16777216, 4096, 65536, 64, 65536, 1024,
                                         1048576, 1024, 393216, 384, 49152, 384,
                                         131072, 1024, 2048, 2};
    bool order_ok = (n_in == 16);
    if (order_ok)
        for (int i = 0; i < 16; i++)
            if (in_sizes[i] != expect_sizes[i]) { order_ok = false; break; }
    float* out = (float*)d_out;
    if (!order_ok) {
        zero_out_kernel<<<dim3(4096), dim3(256), 0, stream>>>(out);
        return;
    }

    const void* x    = d_in[0];
    const void* Amat = d_in[1];
    const void* Bw   = d_in[2];
    const void* Bb   = d_in[3];
    const void* Cw   = d_in[4];
    const void* Cb   = d_in[5];
    const void* Dw   = d_in[6];
    const void* Db   = d_in[7];
    const void* Wih  = d_in[8];
    const void* bih  = d_in[9];
    const void* Whh  = d_in[10];
    const void* bhh  = d_in[11];
    const void* pw   = d_in[12];
    const void* pb   = d_in[13];
    const void* gw   = d_in[14];
    const void* gb   = d_in[15];

    // d_ws base (21.1 MB): flag | gx | hs | hr | bx | ih ; then optional bf16 mirrors
    char* ws = (char*)d_ws;
    int*            flg = (int*)(ws);                        //       256 B (flg[0]=sniff, flg[1]=0)
    float*          gxw = (float*)(ws + 256);                //   131,072 B
    unsigned short* hsw = (unsigned short*)(ws + 131328);    // 2,097,152 B
    unsigned short* hrw = (unsigned short*)(ws + 2228480);   // 4,194,304 B
    unsigned short* bxw = (unsigned short*)(ws + 6422784);   // 2,097,152 B
    unsigned short* ihw = (unsigned short*)(ws + 8519936);   // 12,582,912 B
    // bf16 mirrors (ws-gated)
    unsigned short* xb   = (unsigned short*)(ws + 21102848); // 33,554,432 B
    unsigned short* Dwb  = (unsigned short*)(ws + 54657280); //  2,097,152 B
    unsigned short* Wihb = (unsigned short*)(ws + 56754432); //    786,432 B
    unsigned short* pwb  = (unsigned short*)(ws + 57540864); //    262,144 B
    unsigned short* Cwb  = (unsigned short*)(ws + 57803008); //    131,072 B
    unsigned short* Bwb  = (unsigned short*)(ws + 57934080); //    131,072 B
    unsigned short* bihb = (unsigned short*)(ws + 58065152); //        768 B (4KB slot)
    unsigned short* Bbb  = (unsigned short*)(ws + 58069248);
    unsigned short* Cbb  = (unsigned short*)(ws + 58073344);
    unsigned short* Dbb  = (unsigned short*)(ws + 58077440);
    unsigned short* pbb  = (unsigned short*)(ws + 58081536);
    bool big = ws_size >= 58085632ull;

    dim3 blk(256);
    sniff_kernel<<<dim3(1), dim3(64), 0, stream>>>((const unsigned short*)x, flg);
    if (big) {
        cvt_all_kernel<<<dim3(4513), blk, 0, stream>>>(
            x, Dw, Wih, pw, Cw, Bw, bih, Bb, Cb, Db, pb,
            xb, Dwb, Wihb, pwb, Cwb, Bwb, bihb, Bbb, Cbb, Dbb, pbb, flg);
        gemm_fused_kernel<<<dim3(128, 4), blk, 0, stream>>>(
            xb, Wihb, bihb, ihw, Bwb, Bbb, bxw, flg + 1);
        scan_kernel<<<dim3(3088), dim3(512), 0, stream>>>(
            Amat, Whh, bhh, bxw, ihw, hsw, hrw, x, gw, gb, gxw,
            xb, Dwb, out, flg, flg + 1);
        out_kernel<<<dim3(128, 8), blk, 0, stream>>>(
            Dbb, hsw, Cwb, Cbb, hrw, pwb, pbb, gxw, out, flg + 1);
    } else {
        gemm_fused_kernel<<<dim3(128, 4), blk, 0, stream>>>(
            x, Wih, bih, ihw, Bw, Bb, bxw, flg);
        scan_kernel<<<dim3(3088), dim3(512), 0, stream>>>(
            Amat, Whh, bhh, bxw, ihw, hsw, hrw, x, gw, gb, gxw,
            x, Dw, out, flg, flg);
        out_kernel<<<dim3(128, 8), blk, 0, stream>>>(
            Db, hsw, Cw, Cb, hrw, pw, pb, gxw, out, flg);
    }
}